// Round 3
// baseline (133.684 us; speedup 1.0000x reference)
//
#include <hip/hip_runtime.h>
#include <hip/hip_bf16.h>
#include <stdint.h>

typedef unsigned long long u64;

#define N 8192
#define K 30
#define NWAVE 4                 // waves per block
#define R 2                     // rows per wave
#define RPB (NWAVE * R)         // rows per block = 8
#define CHUNK 512
#define NCHUNK (N / CHUNK)      // 16
#define CAP 352                 // per-row survivor buffer (u64)
#define FLUSH_AT 96             // flush when cnt > FLUSH_AT (influx <= 256 after check)

// ws layout: tbl f32x4[8192] @0 (128KB) | list int[8192] @131072 | ctr int[2] @163840

__global__ void zero_kernel(int* __restrict__ ctr) {
  if (threadIdx.x < 2) ctr[threadIdx.x] = 0;
}

// ---------------- prep: centroid + sq + validity, compact row list ----------------
// All arithmetic via _rn intrinsics (no FMA contraction) to bit-match np f32.
__global__ __launch_bounds__(256) void prep_kernel(const float* __restrict__ X,
                                                   const int* __restrict__ C,
                                                   float4* __restrict__ tbl,
                                                   int* __restrict__ list,
                                                   int* __restrict__ ctr) {
  int i = blockIdx.x * 256 + threadIdx.x;
  if (i >= N) return;
  const float4* xp = (const float4*)(X + (size_t)i * 12);
  float4 f0 = xp[0], f1 = xp[1], f2 = xp[2];
  float mx = __fmul_rn(__fadd_rn(__fadd_rn(__fadd_rn(f0.x, f0.w), f1.z), f2.y), 0.25f);
  float my = __fmul_rn(__fadd_rn(__fadd_rn(__fadd_rn(f0.y, f1.x), f1.w), f2.z), 0.25f);
  float mz = __fmul_rn(__fadd_rn(__fadd_rn(__fadd_rn(f0.z, f1.y), f2.x), f2.w), 0.25f);
  float sq = __fadd_rn(__fadd_rn(__fmul_rn(mx, mx), __fmul_rn(my, my)), __fmul_rn(mz, mz));
  bool valid = (C[i] > 0);
  tbl[i] = make_float4(mx, my, mz, valid ? sq : __builtin_inff());
  if (valid) { int p = atomicAdd(&ctr[0], 1); list[p] = i; }
  else       { int p = atomicAdd(&ctr[1], 1); list[N - 1 - p] = i; }
}

// ---------------- flush: sort survivors, merge into top-64, refresh theta ----------
__device__ __forceinline__ void wave_flush(u64& L, unsigned& th, unsigned& cnt,
                                           volatile u64* buf, int lane) {
  for (unsigned base = 0; base < cnt; base += 64) {
    u64 v = (base + (unsigned)lane < cnt) ? buf[base + lane] : ~0ull;
#pragma unroll
    for (int k = 2; k <= 64; k <<= 1) {
#pragma unroll
      for (int j = k >> 1; j > 0; j >>= 1) {
        u64 o = __shfl_xor(v, j);
        bool lower = (lane & j) == 0;
        bool asc = (lane & k) == 0;
        u64 mn = v < o ? v : o;
        u64 mx = v < o ? o : v;
        v = (lower == asc) ? mn : mx;
      }
    }
    u64 vr = __shfl(v, 63 - lane);   // reverse -> bitonic with L
    u64 m = L < vr ? L : vr;         // 64 smallest of the 128
#pragma unroll
    for (int j = 32; j > 0; j >>= 1) {
      u64 o = __shfl_xor(m, j);
      bool lower = (lane & j) == 0;
      u64 mn = m < o ? m : o;
      u64 mx = m < o ? o : m;
      m = lower ? mn : mx;
    }
    L = m;
  }
  th = (unsigned)(__shfl(L, 29) >> 32);  // key bits of current 30th smallest
  cnt = 0;
}

// exact np f32 arithmetic: mul/add (no fma), sequential sums, sqrt(max+eps)
#define KEYF(Q, P) ({                                                              \
  float _dot = __fadd_rn(__fadd_rn(__fmul_rn((Q).x, (P).x), __fmul_rn((Q).y, (P).y)), \
                         __fmul_rn((Q).z, (P).z));                                 \
  float _d2 = __fsub_rn(__fadd_rn((Q).w, (P).w), __fmul_rn(2.0f, _dot));           \
  sqrtf(__fadd_rn(fmaxf(_d2, 0.0f), 1e-6f)); })

#define PROCESS(RN, MASK, KEYV, JJ)                                                \
  if (MASK) {                                                                      \
    unsigned pos = cnt##RN + (unsigned)__popcll((MASK) & ((1ull << lane) - 1ull)); \
    if (((MASK) >> lane) & 1ull)                                                   \
      buf[w][RN][pos] = ((u64)__float_as_uint(KEYV) << 32) | (unsigned)(JJ);       \
    cnt##RN += (unsigned)__popcll(MASK);                                           \
  }

// ---------------- main: fused distance + top-30, 2 rows per wave ----------------
__global__ __launch_bounds__(256) void knn_kernel(const float4* __restrict__ tbl,
                                                  const int* __restrict__ list,
                                                  const int* __restrict__ ctr,
                                                  __hip_bfloat16* __restrict__ out) {
  __shared__ float4 stage[CHUNK];
  __shared__ u64 buf[NWAVE][R][CAP];

  const int lane = threadIdx.x & 63;
  const int w = threadIdx.x >> 6;
  const int nValid = ctr[0];
  const int pos0 = blockIdx.x * RPB + w * R;
  const int r0 = list[pos0];
  const int r1 = list[pos0 + 1];
  const bool a0 = pos0 < nValid;
  const bool a1 = pos0 + 1 < nValid;
  const bool blockActive = (int)(blockIdx.x * RPB) < nValid;

  const float4 q0 = tbl[r0];
  const float4 q1 = tbl[r1];

  u64 L0 = ~0ull, L1 = ~0ull;
  unsigned th0 = a0 ? 0xFFFFFFFFu : 0u;   // inactive rows never accept
  unsigned th1 = a1 ? 0xFFFFFFFFu : 0u;
  unsigned cnt0 = 0, cnt1 = 0;

  if (blockActive) {
    for (int c = 0; c < NCHUNK; ++c) {
      __syncthreads();
      for (int t = threadIdx.x; t < CHUNK; t += 256)
        stage[t] = tbl[c * CHUNK + t];
      __syncthreads();

      const int jb = c * CHUNK + lane;
#pragma unroll 1
      for (int s = 0; s < CHUNK / 256; ++s) {
        const int sb = s * 256;
        float4 p0 = stage[sb + lane];
        float4 p1 = stage[sb + lane + 64];
        float4 p2 = stage[sb + lane + 128];
        float4 p3 = stage[sb + lane + 192];
        float k00 = KEYF(q0, p0), k01 = KEYF(q0, p1), k02 = KEYF(q0, p2), k03 = KEYF(q0, p3);
        float k10 = KEYF(q1, p0), k11 = KEYF(q1, p1), k12 = KEYF(q1, p2), k13 = KEYF(q1, p3);
        u64 m00 = __ballot(__float_as_uint(k00) <= th0);
        u64 m01 = __ballot(__float_as_uint(k01) <= th0);
        u64 m02 = __ballot(__float_as_uint(k02) <= th0);
        u64 m03 = __ballot(__float_as_uint(k03) <= th0);
        u64 m10 = __ballot(__float_as_uint(k10) <= th1);
        u64 m11 = __ballot(__float_as_uint(k11) <= th1);
        u64 m12 = __ballot(__float_as_uint(k12) <= th1);
        u64 m13 = __ballot(__float_as_uint(k13) <= th1);
        if (m00 | m01 | m02 | m03 | m10 | m11 | m12 | m13) {
          PROCESS(0, m00, k00, jb + sb)
          PROCESS(0, m01, k01, jb + sb + 64)
          PROCESS(0, m02, k02, jb + sb + 128)
          PROCESS(0, m03, k03, jb + sb + 192)
          if (cnt0 > FLUSH_AT) wave_flush(L0, th0, cnt0, &buf[w][0][0], lane);
          PROCESS(1, m10, k10, jb + sb)
          PROCESS(1, m11, k11, jb + sb + 64)
          PROCESS(1, m12, k12, jb + sb + 128)
          PROCESS(1, m13, k13, jb + sb + 192)
          if (cnt1 > FLUSH_AT) wave_flush(L1, th1, cnt1, &buf[w][1][0], lane);
        }
      }
    }
  }
  if (cnt0) wave_flush(L0, th0, cnt0, &buf[w][0][0], lane);
  if (cnt1) wave_flush(L1, th1, cnt1, &buf[w][1][0], lane);

  // ---------------- epilogue ----------------
  if (lane < K) {
    {
      const int o = r0 * K + lane;
      if (a0) {
        out[o] = __float2bfloat16((float)(unsigned)(L0 & 0xFFFFFFFFull));
        out[N * K + o] = __float2bfloat16(__uint_as_float((unsigned)(L0 >> 32)));
        out[2 * N * K + o] = __float2bfloat16(1.0f);
      } else {
        out[o] = __float2bfloat16((float)lane);
        ((unsigned short*)out)[N * K + o] = 0x7F7Fu;   // bf16 max finite (exp=inf)
        out[2 * N * K + o] = __float2bfloat16(0.0f);
      }
    }
    {
      const int o = r1 * K + lane;
      if (a1) {
        out[o] = __float2bfloat16((float)(unsigned)(L1 & 0xFFFFFFFFull));
        out[N * K + o] = __float2bfloat16(__uint_as_float((unsigned)(L1 >> 32)));
        out[2 * N * K + o] = __float2bfloat16(1.0f);
      } else {
        out[o] = __float2bfloat16((float)lane);
        ((unsigned short*)out)[N * K + o] = 0x7F7Fu;
        out[2 * N * K + o] = __float2bfloat16(0.0f);
      }
    }
  }
}

extern "C" void kernel_launch(void* const* d_in, const int* in_sizes, int n_in,
                              void* d_out, int out_size, void* d_ws, size_t ws_size,
                              hipStream_t stream) {
  const float* X = (const float*)d_in[0];
  const int* C = (const int*)d_in[1];
  float4* tbl = (float4*)d_ws;
  int* list = (int*)((char*)d_ws + 131072);
  int* ctr = (int*)((char*)d_ws + 163840);
  __hip_bfloat16* out = (__hip_bfloat16*)d_out;

  zero_kernel<<<1, 64, 0, stream>>>(ctr);
  prep_kernel<<<N / 256, 256, 0, stream>>>(X, C, tbl, list, ctr);
  knn_kernel<<<N / RPB, 256, 0, stream>>>(tbl, list, ctr, out);
}

// Round 4
// 117.040 us; speedup vs baseline: 1.1422x; 1.1422x over previous
//
#include <hip/hip_runtime.h>
#include <hip/hip_bf16.h>
#include <stdint.h>

typedef unsigned long long u64;
typedef float f32x2 __attribute__((ext_vector_type(2)));

#define N 8192
#define K 30
#define NWAVE 2                 // waves per block (block = 128 threads)
#define R 2                     // rows per wave
#define RPB (NWAVE * R)         // rows per block = 4
#define CHUNK 512
#define NCHUNK (N / CHUNK)      // 16
#define CAP 352                 // per-row survivor buffer (u64)
#define FLUSH_AT 224            // check after each 128-influx => cnt <= 352

// ws layout: gx[8192] @0 | gy @32768 | gz @65536 | gw @98304 | list @131072 | ctr @163840

// CDNA packed-f32 helpers (VOP3P, element-wise, default op_sel)
static __device__ __forceinline__ f32x2 pk_mul(f32x2 a, f32x2 b) {
  f32x2 d; asm("v_pk_mul_f32 %0, %1, %2" : "=v"(d) : "v"(a), "v"(b)); return d;
}
static __device__ __forceinline__ f32x2 pk_add(f32x2 a, f32x2 b) {
  f32x2 d; asm("v_pk_add_f32 %0, %1, %2" : "=v"(d) : "v"(a), "v"(b)); return d;
}
static __device__ __forceinline__ f32x2 pk_fma(f32x2 a, f32x2 b, f32x2 c) {
  f32x2 d; asm("v_pk_fma_f32 %0, %1, %2, %3" : "=v"(d) : "v"(a), "v"(b), "v"(c)); return d;
}

__global__ void zero_kernel(int* __restrict__ ctr) {
  if (threadIdx.x < 2) ctr[threadIdx.x] = 0;
}

// ---------------- prep: centroid + sq + validity (SoA), compact row list ----------
// _rn intrinsics everywhere: no FMA contraction, bit-match np f32.
__global__ __launch_bounds__(256) void prep_kernel(const float* __restrict__ X,
                                                   const int* __restrict__ C,
                                                   float* __restrict__ gx,
                                                   float* __restrict__ gy,
                                                   float* __restrict__ gz,
                                                   float* __restrict__ gw,
                                                   int* __restrict__ list,
                                                   int* __restrict__ ctr) {
  int i = blockIdx.x * 256 + threadIdx.x;
  if (i >= N) return;
  const float4* xp = (const float4*)(X + (size_t)i * 12);
  float4 f0 = xp[0], f1 = xp[1], f2 = xp[2];
  float mx = __fmul_rn(__fadd_rn(__fadd_rn(__fadd_rn(f0.x, f0.w), f1.z), f2.y), 0.25f);
  float my = __fmul_rn(__fadd_rn(__fadd_rn(__fadd_rn(f0.y, f1.x), f1.w), f2.z), 0.25f);
  float mz = __fmul_rn(__fadd_rn(__fadd_rn(__fadd_rn(f0.z, f1.y), f2.x), f2.w), 0.25f);
  float sq = __fadd_rn(__fadd_rn(__fmul_rn(mx, mx), __fmul_rn(my, my)), __fmul_rn(mz, mz));
  bool valid = (C[i] > 0);
  gx[i] = mx; gy[i] = my; gz[i] = mz;
  gw[i] = valid ? sq : __builtin_inff();
  if (valid) { int p = atomicAdd(&ctr[0], 1); list[p] = i; }
  else       { int p = atomicAdd(&ctr[1], 1); list[N - 1 - p] = i; }
}

// ---------------- flush: exact D for survivors, sort, merge top-64, new theta ------
// buf entries: (d2_bits << 32) | idx  (order-free storage).  L: (D_bits<<32)|idx asc.
__device__ __forceinline__ void wave_flush(u64& L, float& th, unsigned& cnt,
                                           volatile u64* buf, int lane) {
  for (unsigned base = 0; base < cnt; base += 64) {
    u64 raw = (base + (unsigned)lane < cnt) ? buf[base + lane] : ~0ull;
    u64 v = ~0ull;
    if (raw != ~0ull) {
      float d2 = __uint_as_float((unsigned)(raw >> 32));
      float D = sqrtf(__fadd_rn(fmaxf(d2, 0.0f), 1e-6f));   // exact ref formula
      v = ((u64)__float_as_uint(D) << 32) | (raw & 0xFFFFFFFFull);
    }
#pragma unroll
    for (int k = 2; k <= 64; k <<= 1) {
#pragma unroll
      for (int j = k >> 1; j > 0; j >>= 1) {
        u64 o = __shfl_xor(v, j);
        bool lower = (lane & j) == 0;
        bool asc = (lane & k) == 0;
        u64 mn = v < o ? v : o;
        u64 mx = v < o ? o : v;
        v = (lower == asc) ? mn : mx;
      }
    }
    u64 vr = __shfl(v, 63 - lane);   // reverse -> bitonic with L
    u64 m = L < vr ? L : vr;         // 64 smallest of the 128
#pragma unroll
    for (int j = 32; j > 0; j >>= 1) {
      u64 o = __shfl_xor(m, j);
      bool lower = (lane & j) == 0;
      u64 mn = m < o ? m : o;
      u64 mx = m < o ? o : m;
      m = lower ? mn : mx;
    }
    L = m;
  }
  // conservative d2-space threshold from current 30th D (superset-safe)
  float D30 = __uint_as_float((unsigned)(__shfl(L, 29) >> 32));
  th = __fmul_rn(__fmul_rn(D30, D30), 1.00001f);
  cnt = 0;
}

#define PACK(V, J) (((u64)__float_as_uint(V) << 32) | (unsigned)(J))
#define PROCESS(RN, MASK, D2V, JJ)                                                 \
  if (MASK) {                                                                      \
    unsigned pos = cnt##RN + (unsigned)__popcll((MASK) & ((1ull << lane) - 1ull)); \
    if (((MASK) >> lane) & 1ull) buf[w][RN][pos] = PACK(D2V, JJ);                  \
    cnt##RN += (unsigned)__popcll(MASK);                                           \
  }

// ---------------- main: fused distance + top-30, 2 rows/wave, 2 cands/lane --------
__global__ __launch_bounds__(128) void knn_kernel(const float* __restrict__ gx,
                                                  const float* __restrict__ gy,
                                                  const float* __restrict__ gz,
                                                  const float* __restrict__ gw,
                                                  const int* __restrict__ list,
                                                  const int* __restrict__ ctr,
                                                  __hip_bfloat16* __restrict__ out) {
  __shared__ __align__(16) float sx[CHUNK], sy[CHUNK], sz[CHUNK], sw[CHUNK];
  __shared__ u64 buf[NWAVE][R][CAP];

  const int lane = threadIdx.x & 63;
  const int w = threadIdx.x >> 6;
  const int nValid = ctr[0];
  const int pos0 = blockIdx.x * RPB + w * R;
  const int r0 = list[pos0];
  const int r1 = list[pos0 + 1];
  const bool a0 = pos0 < nValid;
  const bool a1 = pos0 + 1 < nValid;
  const bool blockActive = (int)(blockIdx.x * RPB) < nValid;

  const float q0x = gx[r0], q0y = gy[r0], q0z = gz[r0], q0w = gw[r0];
  const float q1x = gx[r1], q1y = gy[r1], q1z = gz[r1], q1w = gw[r1];
  const f32x2 q0x2 = {q0x, q0x}, q0y2 = {q0y, q0y}, q0z2 = {q0z, q0z}, q0w2 = {q0w, q0w};
  const f32x2 q1x2 = {q1x, q1x}, q1y2 = {q1y, q1y}, q1z2 = {q1z, q1z}, q1w2 = {q1w, q1w};
  const f32x2 neg1 = {-1.0f, -1.0f};

  u64 L0 = ~0ull, L1 = ~0ull;
  float th0 = a0 ? __builtin_inff() : -__builtin_inff();  // inactive never accepts
  float th1 = a1 ? __builtin_inff() : -__builtin_inff();
  unsigned cnt0 = 0, cnt1 = 0;

  auto do_iter = [&](int c, int g) {
    const int lo = g * 64 + lane;                 // f32x2 index in chunk arrays
    f32x2 px = ((const f32x2*)sx)[lo];
    f32x2 py = ((const f32x2*)sy)[lo];
    f32x2 pz = ((const f32x2*)sz)[lo];
    f32x2 pw = ((const f32x2*)sw)[lo];
    // d2 = (q.w + p.w) - 2*dot, replicating np rounding exactly:
    //   dot = (qx*px + qy*py) + qz*pz  (mul/add, left-assoc)
    //   2*dot == dot+dot (exact);  t-u via fma(u,-1,t) (single rounding)
    f32x2 dot0 = pk_add(pk_add(pk_mul(q0x2, px), pk_mul(q0y2, py)), pk_mul(q0z2, pz));
    f32x2 d20 = pk_fma(pk_add(dot0, dot0), neg1, pk_add(q0w2, pw));
    f32x2 dot1 = pk_add(pk_add(pk_mul(q1x2, px), pk_mul(q1y2, py)), pk_mul(q1z2, pz));
    f32x2 d21 = pk_fma(pk_add(dot1, dot1), neg1, pk_add(q1w2, pw));
    u64 me0 = __ballot(d20.x <= th0);
    u64 mo0 = __ballot(d20.y <= th0);
    u64 me1 = __ballot(d21.x <= th1);
    u64 mo1 = __ballot(d21.y <= th1);
    if (me0 | mo0 | me1 | mo1) {
      const int jb = c * CHUNK + g * 128 + 2 * lane;
      if (me0 | mo0) {
        PROCESS(0, me0, d20.x, jb)
        PROCESS(0, mo0, d20.y, jb + 1)
        if (cnt0 > FLUSH_AT) wave_flush(L0, th0, cnt0, &buf[w][0][0], lane);
      }
      if (me1 | mo1) {
        PROCESS(1, me1, d21.x, jb)
        PROCESS(1, mo1, d21.y, jb + 1)
        if (cnt1 > FLUSH_AT) wave_flush(L1, th1, cnt1, &buf[w][1][0], lane);
      }
    }
  };

  if (blockActive) {
    for (int c = 0; c < NCHUNK; ++c) {
      __syncthreads();
      {
        const int t = threadIdx.x;                 // 128 threads x 16B = 2KB/array
        ((float4*)sx)[t] = ((const float4*)(gx + c * CHUNK))[t];
        ((float4*)sy)[t] = ((const float4*)(gy + c * CHUNK))[t];
        ((float4*)sz)[t] = ((const float4*)(gz + c * CHUNK))[t];
        ((float4*)sw)[t] = ((const float4*)(gw + c * CHUNK))[t];
      }
      __syncthreads();
      do_iter(c, 0);
      if (c == 0) {   // prime theta from the first 128 candidates
        if (cnt0) wave_flush(L0, th0, cnt0, &buf[w][0][0], lane);
        if (cnt1) wave_flush(L1, th1, cnt1, &buf[w][1][0], lane);
      }
      do_iter(c, 1);
      do_iter(c, 2);
      do_iter(c, 3);
    }
  }
  if (cnt0) wave_flush(L0, th0, cnt0, &buf[w][0][0], lane);
  if (cnt1) wave_flush(L1, th1, cnt1, &buf[w][1][0], lane);

  // ---------------- epilogue: idx / D / mask as bf16 ----------------
  if (lane < K) {
    {
      const int o = r0 * K + lane;
      if (a0) {
        out[o] = __float2bfloat16((float)(unsigned)(L0 & 0xFFFFFFFFull));
        out[N * K + o] = __float2bfloat16(__uint_as_float((unsigned)(L0 >> 32)));
        out[2 * N * K + o] = __float2bfloat16(1.0f);
      } else {
        out[o] = __float2bfloat16((float)lane);
        ((unsigned short*)out)[N * K + o] = 0x7F7Fu;   // finite vs expected inf
        out[2 * N * K + o] = __float2bfloat16(0.0f);
      }
    }
    {
      const int o = r1 * K + lane;
      if (a1) {
        out[o] = __float2bfloat16((float)(unsigned)(L1 & 0xFFFFFFFFull));
        out[N * K + o] = __float2bfloat16(__uint_as_float((unsigned)(L1 >> 32)));
        out[2 * N * K + o] = __float2bfloat16(1.0f);
      } else {
        out[o] = __float2bfloat16((float)lane);
        ((unsigned short*)out)[N * K + o] = 0x7F7Fu;
        out[2 * N * K + o] = __float2bfloat16(0.0f);
      }
    }
  }
}

extern "C" void kernel_launch(void* const* d_in, const int* in_sizes, int n_in,
                              void* d_out, int out_size, void* d_ws, size_t ws_size,
                              hipStream_t stream) {
  const float* X = (const float*)d_in[0];
  const int* C = (const int*)d_in[1];
  float* gx = (float*)d_ws;
  float* gy = (float*)((char*)d_ws + 32768);
  float* gz = (float*)((char*)d_ws + 65536);
  float* gw = (float*)((char*)d_ws + 98304);
  int* list = (int*)((char*)d_ws + 131072);
  int* ctr = (int*)((char*)d_ws + 163840);
  __hip_bfloat16* out = (__hip_bfloat16*)d_out;

  zero_kernel<<<1, 64, 0, stream>>>(ctr);
  prep_kernel<<<N / 256, 256, 0, stream>>>(X, C, gx, gy, gz, gw, list, ctr);
  knn_kernel<<<N / RPB, 128, 0, stream>>>(gx, gy, gz, gw, list, ctr, out);
}

// Round 5
// 86.206 us; speedup vs baseline: 1.5508x; 1.3577x over previous
//
#include <hip/hip_runtime.h>
#include <hip/hip_bf16.h>
#include <stdint.h>

typedef unsigned long long u64;
typedef float f32x2 __attribute__((ext_vector_type(2)));

#define N 8192
#define K 30
#define NWAVE 4                 // waves per block (256 threads), free-running
#define R 2                     // rows per wave
#define RPB (NWAVE * R)         // rows per block = 8
#define CAP 224                 // per-row survivor buffer (u64)
#define FLUSH_AT 96             // flush when cnt > 96 (influx <= 128/iter => cnt <= 224)

// ws layout: gx[8192] @0 | gy @32768 | gz @65536 | gw @98304 | list @131072 | ctr @163840

// CDNA packed-f32 (VOP3P): 2 candidates per instruction
static __device__ __forceinline__ f32x2 pk_mul(f32x2 a, f32x2 b) {
  f32x2 d; asm("v_pk_mul_f32 %0, %1, %2" : "=v"(d) : "v"(a), "v"(b)); return d;
}
static __device__ __forceinline__ f32x2 pk_add(f32x2 a, f32x2 b) {
  f32x2 d; asm("v_pk_add_f32 %0, %1, %2" : "=v"(d) : "v"(a), "v"(b)); return d;
}
static __device__ __forceinline__ f32x2 pk_fma(f32x2 a, f32x2 b, f32x2 c) {
  f32x2 d; asm("v_pk_fma_f32 %0, %1, %2, %3" : "=v"(d) : "v"(a), "v"(b), "v"(c)); return d;
}

__global__ void zero_kernel(int* __restrict__ ctr) {
  if (threadIdx.x < 2) ctr[threadIdx.x] = 0;
}

// ---------------- prep: centroid + sq + validity (SoA), compact row list ----------
// _rn intrinsics everywhere: no FMA contraction, bit-match np f32.
__global__ __launch_bounds__(256) void prep_kernel(const float* __restrict__ X,
                                                   const int* __restrict__ C,
                                                   float* __restrict__ gx,
                                                   float* __restrict__ gy,
                                                   float* __restrict__ gz,
                                                   float* __restrict__ gw,
                                                   int* __restrict__ list,
                                                   int* __restrict__ ctr) {
  int i = blockIdx.x * 256 + threadIdx.x;
  if (i >= N) return;
  const float4* xp = (const float4*)(X + (size_t)i * 12);
  float4 f0 = xp[0], f1 = xp[1], f2 = xp[2];
  float mx = __fmul_rn(__fadd_rn(__fadd_rn(__fadd_rn(f0.x, f0.w), f1.z), f2.y), 0.25f);
  float my = __fmul_rn(__fadd_rn(__fadd_rn(__fadd_rn(f0.y, f1.x), f1.w), f2.z), 0.25f);
  float mz = __fmul_rn(__fadd_rn(__fadd_rn(__fadd_rn(f0.z, f1.y), f2.x), f2.w), 0.25f);
  float sq = __fadd_rn(__fadd_rn(__fmul_rn(mx, mx), __fmul_rn(my, my)), __fmul_rn(mz, mz));
  bool valid = (C[i] > 0);
  gx[i] = mx; gy[i] = my; gz[i] = mz;
  gw[i] = valid ? sq : __builtin_inff();
  if (valid) { int p = atomicAdd(&ctr[0], 1); list[p] = i; }
  else       { int p = atomicAdd(&ctr[1], 1); list[N - 1 - p] = i; }
}

// ---------------- flush: exact D for survivors, sort, merge top-64, new theta ------
// buf entries: (d2_bits<<32)|idx.  L: (D_bits<<32)|idx ascending across lanes.
__device__ __forceinline__ void wave_flush(u64& L, float& th, unsigned& cnt,
                                           volatile u64* buf, int lane) {
  for (unsigned base = 0; base < cnt; base += 64) {
    u64 raw = (base + (unsigned)lane < cnt) ? buf[base + lane] : ~0ull;
    u64 v = ~0ull;
    if (raw != ~0ull) {
      float d2 = __uint_as_float((unsigned)(raw >> 32));
      float D = sqrtf(__fadd_rn(fmaxf(d2, 0.0f), 1e-6f));   // exact ref formula
      v = ((u64)__float_as_uint(D) << 32) | (raw & 0xFFFFFFFFull);
    }
#pragma unroll
    for (int k = 2; k <= 64; k <<= 1) {
#pragma unroll
      for (int j = k >> 1; j > 0; j >>= 1) {
        u64 o = __shfl_xor(v, j);
        bool lower = (lane & j) == 0;
        bool asc = (lane & k) == 0;
        u64 mn = v < o ? v : o;
        u64 mx = v < o ? o : v;
        v = (lower == asc) ? mn : mx;
      }
    }
    u64 vr = __shfl(v, 63 - lane);   // reverse -> bitonic with L
    u64 m = L < vr ? L : vr;         // 64 smallest of the 128
#pragma unroll
    for (int j = 32; j > 0; j >>= 1) {
      u64 o = __shfl_xor(m, j);
      bool lower = (lane & j) == 0;
      u64 mn = m < o ? m : o;
      u64 mx = m < o ? o : m;
      m = lower ? mn : mx;
    }
    L = m;
  }
  // conservative d2-space threshold from current 30th D (superset-safe)
  float D30 = __uint_as_float((unsigned)(__shfl(L, 29) >> 32));
  th = __fmul_rn(__fmul_rn(D30, D30), 1.00001f);
  cnt = 0;
}

#define PACK(V, J) (((u64)__float_as_uint(V) << 32) | (unsigned)(J))
#define PROCESS(RN, MASK, D2V, JJ)                                                 \
  if (MASK) {                                                                      \
    unsigned pos = cnt##RN + (unsigned)__popcll((MASK) & ((1ull << lane) - 1ull)); \
    if (((MASK) >> lane) & 1ull) buf[w][RN][pos] = PACK(D2V, JJ);                  \
    cnt##RN += (unsigned)__popcll(MASK);                                           \
  }

__device__ __forceinline__ void write_row(int r, bool act, u64 L, int lane,
                                          __hip_bfloat16* __restrict__ out) {
  if (lane >= K) return;
  const int o = r * K + lane;
  if (act) {
    out[o] = __float2bfloat16((float)(unsigned)(L & 0xFFFFFFFFull));
    out[N * K + o] = __float2bfloat16(__uint_as_float((unsigned)(L >> 32)));
    out[2 * N * K + o] = __float2bfloat16(1.0f);
  } else {
    out[o] = __float2bfloat16((float)lane);
    ((unsigned short*)out)[N * K + o] = 0x7F7Fu;   // finite bf16-max vs expected inf
    out[2 * N * K + o] = __float2bfloat16(0.0f);
  }
}

// ------- main: barrier-free, L2-direct streaming, 2 rows/wave, 2 cands/lane -------
__global__ __launch_bounds__(256) void knn_kernel(const float* __restrict__ gx,
                                                  const float* __restrict__ gy,
                                                  const float* __restrict__ gz,
                                                  const float* __restrict__ gw,
                                                  const int* __restrict__ list,
                                                  const int* __restrict__ ctr,
                                                  __hip_bfloat16* __restrict__ out) {
  __shared__ u64 buf[NWAVE][R][CAP];

  const int lane = threadIdx.x & 63;
  const int w = threadIdx.x >> 6;
  const int nValid = ctr[0];
  const int pos0 = blockIdx.x * RPB + w * R;
  const int r0 = list[pos0];
  const int r1 = list[pos0 + 1];
  const bool a0 = pos0 < nValid;
  const bool a1 = pos0 + 1 < nValid;

  if (!a0) {                 // whole wave inactive: write + leave immediately
    write_row(r0, false, 0, lane, out);
    write_row(r1, false, 0, lane, out);
    return;
  }

  const float q0x = gx[r0], q0y = gy[r0], q0z = gz[r0], q0w = gw[r0];
  const float q1x = gx[r1], q1y = gy[r1], q1z = gz[r1], q1w = gw[r1];
  const f32x2 q0x2 = {q0x, q0x}, q0y2 = {q0y, q0y}, q0z2 = {q0z, q0z}, q0w2 = {q0w, q0w};
  const f32x2 q1x2 = {q1x, q1x}, q1y2 = {q1y, q1y}, q1z2 = {q1z, q1z}, q1w2 = {q1w, q1w};
  const f32x2 neg1 = {-1.0f, -1.0f};

  u64 L0 = ~0ull, L1 = ~0ull;
  float th0 = __builtin_inff();
  float th1 = a1 ? __builtin_inff() : -__builtin_inff();  // inactive row1 never accepts
  unsigned cnt0 = 0, cnt1 = 0;

  const f32x2* bx = (const f32x2*)gx;
  const f32x2* by = (const f32x2*)gy;
  const f32x2* bz = (const f32x2*)gz;
  const f32x2* bw = (const f32x2*)gw;

  int idx = lane;                       // f32x2 index
  f32x2 px = bx[idx], py = by[idx], pz = bz[idx], pw = bw[idx];

#pragma unroll 2
  for (int it = 0; it < 64; ++it) {
    // prefetch next iteration (clamped re-read on the last — harmless)
    const int nidx = (it < 63) ? idx + 64 : idx;
    f32x2 nx = bx[nidx], ny = by[nidx], nz = bz[nidx], nw = bw[nidx];

    // d2 = (q.w + p.w) - 2*dot with exact np f32 rounding:
    // dot = (qx*px + qy*py) + qz*pz ; 2*dot == dot+dot (exact) ; t-u = fma(u,-1,t)
    f32x2 dot0 = pk_add(pk_add(pk_mul(q0x2, px), pk_mul(q0y2, py)), pk_mul(q0z2, pz));
    f32x2 d20 = pk_fma(pk_add(dot0, dot0), neg1, pk_add(q0w2, pw));
    f32x2 dot1 = pk_add(pk_add(pk_mul(q1x2, px), pk_mul(q1y2, py)), pk_mul(q1z2, pz));
    f32x2 d21 = pk_fma(pk_add(dot1, dot1), neg1, pk_add(q1w2, pw));
    u64 me0 = __ballot(d20.x <= th0);
    u64 mo0 = __ballot(d20.y <= th0);
    u64 me1 = __ballot(d21.x <= th1);
    u64 mo1 = __ballot(d21.y <= th1);
    if (me0 | mo0 | me1 | mo1) {
      const int jb = it * 128 + 2 * lane;
      if (me0 | mo0) {
        PROCESS(0, me0, d20.x, jb)
        PROCESS(0, mo0, d20.y, jb + 1)
        if (cnt0 > FLUSH_AT) wave_flush(L0, th0, cnt0, &buf[w][0][0], lane);
      }
      if (me1 | mo1) {
        PROCESS(1, me1, d21.x, jb)
        PROCESS(1, mo1, d21.y, jb + 1)
        if (cnt1 > FLUSH_AT) wave_flush(L1, th1, cnt1, &buf[w][1][0], lane);
      }
    }
    px = nx; py = ny; pz = nz; pw = nw;
    idx = nidx;
  }

  if (cnt0) wave_flush(L0, th0, cnt0, &buf[w][0][0], lane);
  if (cnt1) wave_flush(L1, th1, cnt1, &buf[w][1][0], lane);

  write_row(r0, true, L0, lane, out);
  write_row(r1, a1, L1, lane, out);
}

extern "C" void kernel_launch(void* const* d_in, const int* in_sizes, int n_in,
                              void* d_out, int out_size, void* d_ws, size_t ws_size,
                              hipStream_t stream) {
  const float* X = (const float*)d_in[0];
  const int* C = (const int*)d_in[1];
  float* gx = (float*)d_ws;
  float* gy = (float*)((char*)d_ws + 32768);
  float* gz = (float*)((char*)d_ws + 65536);
  float* gw = (float*)((char*)d_ws + 98304);
  int* list = (int*)((char*)d_ws + 131072);
  int* ctr = (int*)((char*)d_ws + 163840);
  __hip_bfloat16* out = (__hip_bfloat16*)d_out;

  zero_kernel<<<1, 64, 0, stream>>>(ctr);
  prep_kernel<<<N / 256, 256, 0, stream>>>(X, C, gx, gy, gz, gw, list, ctr);
  knn_kernel<<<N / RPB, 256, 0, stream>>>(gx, gy, gz, gw, list, ctr, out);
}